// Round 8
// baseline (37.484 us; speedup 1.0000x reference)
//
#include <hip/hip_runtime.h>
#include <math.h>

// Problem constants: Q=4, N=64, H=256, C=1, L=1024
#define QQ 4
#define NN 64
#define HH 256

// ws float layout:
//   [0, 524288)          pole tables: 128 float4 per (q,h)   (2 MB)
//   [524288, 525312)     per-(q,h) sum of B*C                (4 KB)
//   [525312, 525824)     tan(pi*l/1024), l=0..511            (2 KB)
//   [525824, 526848)     X512 per (q,h)                      (4 KB)
//   [1048576, 2097152)   spectrum X [Q*H][512] float2        (4 MB)
//   [2097152, 3145728)   time-domain x [Q*H][1024] float     (4 MB)
#define TAB_F4_PER_QH 128
#define SUMS_OFF      524288
#define TAN_OFF       525312
#define XT_OFF        525824
#define XSPEC_OFF     1048576
#define XBUF_OFF      2097152

__device__ __forceinline__ float vcos(float rev) { return __builtin_amdgcn_cosf(rev); }
__device__ __forceinline__ float vsin(float rev) { return __builtin_amdgcn_sinf(rev); }

// ---------- Kernel 0: pole tables + B*C sums + tangent table ----------
__global__ __launch_bounds__(256)
void tssm_prep(const float* __restrict__ diagonal,      // [Q][N]
               const float* __restrict__ lowrank,       // [Q][N]
               const float* __restrict__ input_matrix,  // [Q][N]
               const float* __restrict__ output_matrix, // [Q][1][H][N]
               float* __restrict__ ws)
{
    const int blk = blockIdx.x;
    const int tid = threadIdx.x;

    if (blk >= 256) {               // tangent table: l = (blk-256)*256 + tid
        int l = ((blk - 256) << 8) + tid;
        float f = (float)l * (1.0f / 1024.0f);
        ws[TAN_OFF + l] = sinpif(f) * __builtin_amdgcn_rcpf(cospif(f));
        return;
    }

    const int gt = blk * 256 + tid;   // 0..65535
    const int qh = gt >> 6;
    const int n  = gt & 63;
    const int q  = qh >> 8;

    float a  = __expf(diagonal[q * NN + n]);
    float B  = input_matrix[q * NN + n];
    float P  = lowrank[q * NN + n];
    float Cm = output_matrix[qh * NN + n];
    float w0 = B * Cm;

    float4* tab = (float4*)ws + (size_t)qh * TAB_F4_PER_QH;
    tab[2 * n]     = make_float4(a, a * a, w0, B * P);
    tab[2 * n + 1] = make_float4(P * Cm, P * P, 0.0f, 0.0f);

    float acc = w0;
    #pragma unroll
    for (int off = 32; off >= 1; off >>= 1) acc += __shfl_xor(acc, off, 64);
    if (n == 0) ws[SUMS_OFF + qh] = acc;
}

// ---------- Kernel A: spectrum X[l], 2 blocks per (q,h), 1 bin/thread ----------
__global__ __launch_bounds__(256)
void tssm_spec(const float* __restrict__ timestep,   // [Q][H]
               const float4* __restrict__ tab,       // [Q*H][128]
               const float* __restrict__ sums,       // [Q*H]
               const float* __restrict__ tanl,       // [512]
               float2* __restrict__ xspec,           // [Q*H][512]
               float* __restrict__ xt)               // [Q*H] X512
{
    const int bi   = blockIdx.x;       // 0..2047
    const int qh   = bi >> 1;
    const int half = bi & 1;
    const int t    = threadIdx.x;      // 0..255
    const int l    = (half << 8) + t;  // 0..511

    const float tv   = __expf(timestep[qh]);
    const float invt = __builtin_amdgcn_rcpf(tv);

    const float tn = tanl[l];
    const float ze = 2.0f * tn * invt;
    const float z2 = ze * ze;

    const float4* __restrict__ tq = tab + (size_t)qh * TAB_F4_PER_QH;

    // Re k_j = sum w_j*a*g ; S_j = sum w_j*g ; Im k_j = -ze*S_j
    float r_0=0,r_1=0,r_2=0,r_3=0, s_0=0,s_1=0,s_2=0,s_3=0;
    #pragma unroll 8
    for (int n = 0; n < NN; ++n) {
        float4 A4 = tq[2 * n];        // (a, a2, w0, w1) — uniform address
        float4 B4 = tq[2 * n + 1];    // (w2, w3, -, -)
        float g  = __builtin_amdgcn_rcpf(A4.y + z2);
        float ag = A4.x * g;
        r_0 = fmaf(A4.z, ag, r_0); s_0 = fmaf(A4.z, g, s_0);
        r_1 = fmaf(A4.w, ag, r_1); s_1 = fmaf(A4.w, g, s_1);
        r_2 = fmaf(B4.x, ag, r_2); s_2 = fmaf(B4.x, g, s_2);
        r_3 = fmaf(B4.y, ag, r_3); s_3 = fmaf(B4.y, g, s_3);
    }
    {
        float i0 = -ze * s_0, i1 = -ze * s_1, i2 = -ze * s_2, i3 = -ze * s_3;
        float dr = 1.0f + r_3, di = i3;
        float nr = r_2 * r_1 - i2 * i1;
        float ni = r_2 * i1 + i2 * r_1;
        float invm = __builtin_amdgcn_rcpf(fmaf(dr, dr, di * di));
        float qr = (nr * dr + ni * di) * invm;
        float qi = (ni * dr - nr * di) * invm;
        float Kr = r_0 - qr, Ki = i0 - qi;
        xspec[((size_t)qh << 9) + l] =
            make_float2(fmaf(-tn, Ki, Kr), fmaf(tn, Kr, Ki));
    }
    if (half == 0 && t == 0) xt[qh] = 0.5f * tv * sums[qh];
}

// ---------- Kernel B: 512-pt inverse Stockham FFT per (q,h) ----------
__global__ __launch_bounds__(512)
void tssm_fft(const float2* __restrict__ xspec,   // [Q*H][512]
              const float* __restrict__ xt,       // [Q*H]
              float2* __restrict__ xout)          // [Q*H][512]
{
    __shared__ __align__(16) float2 bufA[512];
    __shared__ __align__(16) float2 bufB[512];

    const int qh = blockIdx.x;        // 0..1023
    const int t  = threadIdx.x;       // 0..511

    // ---------------- Y build (k = t) ----------------
    {
        const float2* __restrict__ Xq = xspec + ((size_t)qh << 9);
        float2 A  = Xq[t];
        float2 Bv = (t == 0) ? make_float2(xt[qh], 0.0f) : Xq[512 - t];
        float c1 = vcos((float)t * 0.0009765625f);   // 2*pi*t/1024
        float s1 = vsin((float)t * 0.0009765625f);
        float Dr = A.x - Bv.x, Di = A.y + Bv.y;
        float twDr = fmaf(c1, Dr, -s1 * Di);
        float twDi = fmaf(c1, Di,  s1 * Dr);
        bufA[t] = make_float2(0.5f * (A.x + Bv.x) - 0.5f * twDi,
                              0.5f * (A.y - Bv.y) + 0.5f * twDr);
    }
    __syncthreads();

    // ------------- Stages (output-centric: thread t owns output point t) ----
    #define FFT_STAGE(NS, LOG2NS, REVNS, SRC, DST)                        \
    {                                                                     \
        int rr   = t & (2 * (NS) - 1);                                    \
        int base = rr & ((NS) - 1);                                       \
        int j    = ((t >> ((LOG2NS) + 1)) << (LOG2NS)) | base;            \
        float2 u = (SRC)[j];                                              \
        float2 v = (SRC)[j + 256];                                        \
        float rev = (float)base * (REVNS);                                \
        float cw = vcos(rev), sw = vsin(rev);                             \
        float vr = fmaf(cw, v.x, -sw * v.y);                              \
        float vi = fmaf(cw, v.y,  sw * v.x);                              \
        float sg = (rr < (NS)) ? 1.0f : -1.0f;                            \
        (DST)[t] = make_float2(fmaf(sg, vr, u.x), fmaf(sg, vi, u.y));     \
        __syncthreads();                                                  \
    }

    FFT_STAGE(1,   0, 0.5f,         bufA, bufB)
    FFT_STAGE(2,   1, 0.25f,        bufB, bufA)
    FFT_STAGE(4,   2, 0.125f,       bufA, bufB)
    FFT_STAGE(8,   3, 0.0625f,      bufB, bufA)
    FFT_STAGE(16,  4, 0.03125f,     bufA, bufB)
    FFT_STAGE(32,  5, 0.015625f,    bufB, bufA)
    FFT_STAGE(64,  6, 0.0078125f,   bufA, bufB)
    FFT_STAGE(128, 7, 0.00390625f,  bufB, bufA)
    #undef FFT_STAGE

    // ---------------- Stage Ns=256 -> coalesced store ----------------
    {
        int base = t & 255;
        float2 u = bufA[base];
        float2 v = bufA[base + 256];
        float rev = (float)base * 0.001953125f;      // base/512 revolutions
        float cw = vcos(rev), sw = vsin(rev);
        float vr = fmaf(cw, v.x, -sw * v.y);
        float vi = fmaf(cw, v.y,  sw * v.x);
        float sg = (t < 256) ? 1.0f : -1.0f;
        const float sc = 1.0f / 512.0f;
        xout[((size_t)qh << 9) + t] =
            make_float2(fmaf(sg, vr, u.x) * sc, fmaf(sg, vi, u.y) * sc);
    }
}

// ---------- Kernel C: x[q][h][s] -> out[s][q][h] ----------
__global__ __launch_bounds__(256)
void tssm_transpose(const float* __restrict__ x, float* __restrict__ out)
{
    __shared__ float tile[64][65];
    const int t  = threadIdx.x;
    const int hs = blockIdx.x;        // 0..3
    const int ss = blockIdx.y;        // 0..15
    const int q  = blockIdx.z;        // 0..3
    const int c  = t & 63;
    const int r0 = t >> 6;
    const int hbase = (q << 8) + (hs << 6);

    #pragma unroll
    for (int rr = 0; rr < 64; rr += 4) {
        int hh = hbase + rr + r0;
        tile[rr + r0][c] = x[(hh << 10) + (ss << 6) + c];
    }
    __syncthreads();
    #pragma unroll
    for (int rr = 0; rr < 64; rr += 4) {
        int s = (ss << 6) + rr + r0;
        out[(s << 10) + hbase + c] = tile[c][rr + r0];
    }
}

extern "C" void kernel_launch(void* const* d_in, const int* in_sizes, int n_in,
                              void* d_out, int out_size, void* d_ws, size_t ws_size,
                              hipStream_t stream) {
    (void)in_sizes; (void)n_in; (void)out_size; (void)ws_size;
    const float* diagonal      = (const float*)d_in[0];
    const float* lowrank       = (const float*)d_in[1];
    const float* timestep      = (const float*)d_in[2];
    const float* input_matrix  = (const float*)d_in[3];
    const float* output_matrix = (const float*)d_in[4];
    float* ws  = (float*)d_ws;
    float* out = (float*)d_out;

    const float4* tabp  = (const float4*)ws;
    const float*  sumsp = ws + SUMS_OFF;
    const float*  tanp  = ws + TAN_OFF;
    float*        xtp   = ws + XT_OFF;
    float2*       xsp   = (float2*)(ws + XSPEC_OFF);
    float2*       xop   = (float2*)(ws + XBUF_OFF);
    const float*  xinp  = ws + XBUF_OFF;

    hipLaunchKernelGGL(tssm_prep, dim3(258), dim3(256), 0, stream,
                       diagonal, lowrank, input_matrix, output_matrix, ws);
    hipLaunchKernelGGL(tssm_spec, dim3(2 * QQ * HH), dim3(256), 0, stream,
                       timestep, tabp, sumsp, tanp, xsp, xtp);
    hipLaunchKernelGGL(tssm_fft, dim3(QQ * HH), dim3(512), 0, stream,
                       (const float2*)xsp, xtp, xop);
    hipLaunchKernelGGL(tssm_transpose, dim3(4, 16, 4), dim3(256), 0, stream,
                       xinp, out);
}

// Round 9
// 28.546 us; speedup vs baseline: 1.3131x; 1.3131x over previous
//
#include <hip/hip_runtime.h>
#include <math.h>

// Problem constants: Q=4, N=64, H=256, C=1, L=1024
#define QQ 4
#define NN 64
#define HH 256

// ws float layout:
//   [0, 524288)        pole tables: 8 floats per pole, 512 per (q,h)  (2 MB)
//   [524288, 525312)   per-(q,h) sum of B*C                           (4 KB)
//   [525312, 525824)   tan(pi*l/1024), l=0..511                       (2 KB)
//   [1048576, 2097152) x buffer [Q*H][1024]                           (4 MB)
#define SUMS_OFF      524288
#define TAN_OFF       525312
#define XBUF_OFF      1048576

typedef int v16i __attribute__((ext_vector_type(16)));

__device__ __forceinline__ float vcos(float rev) { return __builtin_amdgcn_cosf(rev); }
__device__ __forceinline__ float vsin(float rev) { return __builtin_amdgcn_sinf(rev); }

// ---------- Kernel 0: pole tables (8 floats/pole) + B*C sums + tan table ----------
__global__ __launch_bounds__(256)
void tssm_prep(const float* __restrict__ diagonal,      // [Q][N]
               const float* __restrict__ lowrank,       // [Q][N]
               const float* __restrict__ input_matrix,  // [Q][N]
               const float* __restrict__ output_matrix, // [Q][1][H][N]
               float* __restrict__ ws)
{
    const int blk = blockIdx.x;
    const int tid = threadIdx.x;

    if (blk >= 256) {               // tangent table: l = (blk-256)*256 + tid
        int l = ((blk - 256) << 8) + tid;
        float f = (float)l * (1.0f / 1024.0f);
        ws[TAN_OFF + l] = sinpif(f) * __builtin_amdgcn_rcpf(cospif(f));
        return;
    }

    const int gt = blk * 256 + tid;   // 0..65535
    const int qh = gt >> 6;
    const int n  = gt & 63;
    const int q  = qh >> 8;

    float a  = __expf(diagonal[q * NN + n]);
    float B  = input_matrix[q * NN + n];
    float P  = lowrank[q * NN + n];
    float Cm = output_matrix[qh * NN + n];
    float w0 = B * Cm;

    float4* rec = (float4*)ws + ((size_t)(qh * NN + n) << 1);
    rec[0] = make_float4(a, a * a, w0, B * P);
    rec[1] = make_float4(P * Cm, P * P, 0.0f, 0.0f);

    float acc = w0;
    #pragma unroll
    for (int off = 32; off >= 1; off >>= 1) acc += __shfl_xor(acc, off, 64);
    if (n == 0) ws[SUMS_OFF + qh] = acc;
}

// ---------- Kernel 1: spectrum (SGPR-streamed poles) + 512-pt inverse FFT ----------
__global__ __launch_bounds__(256)
void tssm_main(const float* __restrict__ timestep,   // [Q][H]
               const float* __restrict__ tab,        // [Q*H][512] floats
               const float* __restrict__ sums,       // [Q*H]
               const float* __restrict__ tanl,       // [512]
               float2* __restrict__ xout)            // [Q*H][512]
{
    __shared__ __align__(16) float2 bufA[512];
    __shared__ __align__(16) float2 bufB[513];

    const int qh = blockIdx.x;        // 0..1023
    const int t  = threadIdx.x;       // 0..255

    const float tv   = __expf(timestep[qh]);
    const float invt = __builtin_amdgcn_rcpf(tv);

    // ---------------- Phase A: bins l = t and l = t+256 ----------------
    const float tn0 = tanl[t];
    const float tn1 = tanl[t + 256];
    const float ze0 = 2.0f * tn0 * invt, ze1 = 2.0f * tn1 * invt;
    const float z20 = ze0 * ze0,         z21 = ze1 * ze1;

    float r0_0=0,r0_1=0,r0_2=0,r0_3=0, s0_0=0,s0_1=0,s0_2=0,s0_3=0;
    float r1_0=0,r1_1=0,r1_2=0,r1_3=0, s1_0=0,s1_1=0,s1_2=0,s1_3=0;

    const int* tp = (const int*)tab + ((size_t)qh << 9);   // 512 dwords per qh

    // 8 iterations x 8 poles; each pole record = 8 dwords (a,a2,w0,w1,w2,w3,-,-)
    for (int it = 0; it < 8; ++it) {
        v16i G0, G1, G2, G3;   // 2 poles each
        asm volatile(
            "s_load_dwordx16 %0, %4, 0x0\n\t"
            "s_load_dwordx16 %1, %4, 0x40\n\t"
            "s_load_dwordx16 %2, %4, 0x80\n\t"
            "s_load_dwordx16 %3, %4, 0xc0\n\t"
            "s_waitcnt lgkmcnt(0)"
            : "=&s"(G0), "=&s"(G1), "=&s"(G2), "=&s"(G3)
            : "s"(tp));
        tp += 64;   // 256 bytes = 8 poles

        #define DO_POLE(GV, OFF)                                              \
        {                                                                     \
            float a  = __int_as_float((GV)[(OFF) + 0]);                       \
            float a2 = __int_as_float((GV)[(OFF) + 1]);                       \
            float w0 = __int_as_float((GV)[(OFF) + 2]);                       \
            float w1 = __int_as_float((GV)[(OFF) + 3]);                       \
            float w2 = __int_as_float((GV)[(OFF) + 4]);                       \
            float w3 = __int_as_float((GV)[(OFF) + 5]);                       \
            {                                                                 \
                float g  = __builtin_amdgcn_rcpf(a2 + z20);                   \
                float ag = a * g;                                             \
                r0_0 = fmaf(w0, ag, r0_0); s0_0 = fmaf(w0, g, s0_0);          \
                r0_1 = fmaf(w1, ag, r0_1); s0_1 = fmaf(w1, g, s0_1);          \
                r0_2 = fmaf(w2, ag, r0_2); s0_2 = fmaf(w2, g, s0_2);          \
                r0_3 = fmaf(w3, ag, r0_3); s0_3 = fmaf(w3, g, s0_3);          \
            }                                                                 \
            {                                                                 \
                float g  = __builtin_amdgcn_rcpf(a2 + z21);                   \
                float ag = a * g;                                             \
                r1_0 = fmaf(w0, ag, r1_0); s1_0 = fmaf(w0, g, s1_0);          \
                r1_1 = fmaf(w1, ag, r1_1); s1_1 = fmaf(w1, g, s1_1);          \
                r1_2 = fmaf(w2, ag, r1_2); s1_2 = fmaf(w2, g, s1_2);          \
                r1_3 = fmaf(w3, ag, r1_3); s1_3 = fmaf(w3, g, s1_3);          \
            }                                                                 \
        }
        DO_POLE(G0, 0) DO_POLE(G0, 8)
        DO_POLE(G1, 0) DO_POLE(G1, 8)
        DO_POLE(G2, 0) DO_POLE(G2, 8)
        DO_POLE(G3, 0) DO_POLE(G3, 8)
        #undef DO_POLE
    }

    {   // bin l = t
        float i0 = -ze0 * s0_0, i1 = -ze0 * s0_1, i2 = -ze0 * s0_2, i3 = -ze0 * s0_3;
        float dr = 1.0f + r0_3, di = i3;
        float nr = r0_2 * r0_1 - i2 * i1;
        float ni = r0_2 * i1 + i2 * r0_1;
        float invm = __builtin_amdgcn_rcpf(fmaf(dr, dr, di * di));
        float qr = (nr * dr + ni * di) * invm;
        float qi = (ni * dr - nr * di) * invm;
        float Kr = r0_0 - qr, Ki = i0 - qi;
        bufB[t] = make_float2(fmaf(-tn0, Ki, Kr), fmaf(tn0, Kr, Ki));
    }
    {   // bin l = t + 256
        float i0 = -ze1 * s1_0, i1 = -ze1 * s1_1, i2 = -ze1 * s1_2, i3 = -ze1 * s1_3;
        float dr = 1.0f + r1_3, di = i3;
        float nr = r1_2 * r1_1 - i2 * i1;
        float ni = r1_2 * i1 + i2 * r1_1;
        float invm = __builtin_amdgcn_rcpf(fmaf(dr, dr, di * di));
        float qr = (nr * dr + ni * di) * invm;
        float qi = (ni * dr - nr * di) * invm;
        float Kr = r1_0 - qr, Ki = i0 - qi;
        bufB[t + 256] = make_float2(fmaf(-tn1, Ki, Kr), fmaf(tn1, Kr, Ki));
    }
    if (t == 0) bufB[512] = make_float2(0.5f * tv * sums[qh], 0.0f);
    __syncthreads();

    // ---------------- Y build ----------------
    const float c1 = vcos((float)t * 0.0009765625f);   // cos(2*pi*t/1024)
    const float s1 = vsin((float)t * 0.0009765625f);

    float Y0r, Y0i, Y1r, Y1i;
    {   // k = t
        float2 A = bufB[t], Bv = bufB[512 - t];
        float Dr = A.x - Bv.x, Di = A.y + Bv.y;
        float twDr = fmaf(c1, Dr, -s1 * Di);
        float twDi = fmaf(c1, Di,  s1 * Dr);
        Y0r = 0.5f * (A.x + Bv.x) - 0.5f * twDi;
        Y0i = 0.5f * (A.y - Bv.y) + 0.5f * twDr;
    }
    {   // k = t+256
        float2 A = bufB[t + 256], Bv = bufB[256 - t];
        float Dr = A.x - Bv.x, Di = A.y + Bv.y;
        float twDr = fmaf(-s1, Dr, -c1 * Di);
        float twDi = fmaf(-s1, Di,  c1 * Dr);
        Y1r = 0.5f * (A.x + Bv.x) - 0.5f * twDi;
        Y1i = 0.5f * (A.y - Bv.y) + 0.5f * twDr;
    }

    // ---------------- Stage Ns=1 (registers) ----------------
    ((float4*)bufA)[t] = make_float4(Y0r + Y1r, Y0i + Y1i, Y0r - Y1r, Y0i - Y1i);
    __syncthreads();

    // ---------------- Stages Ns = 2..128 ----------------
    #define FFT_STAGE(NS, REVNS, SRC, DST)                                   \
    {                                                                        \
        float2 u = (SRC)[t];                                                 \
        float2 v = (SRC)[t + 256];                                           \
        int   base = t & ((NS) - 1);                                         \
        float rev = (float)base * (REVNS);                                   \
        float cw = vcos(rev), sw = vsin(rev);                                \
        float vr = fmaf(cw, v.x, -sw * v.y);                                 \
        float vi = fmaf(cw, v.y,  sw * v.x);                                 \
        int dj = ((t & ~((NS) - 1)) << 1) | base;                            \
        (DST)[dj]        = make_float2(u.x + vr, u.y + vi);                  \
        (DST)[dj + (NS)] = make_float2(u.x - vr, u.y - vi);                  \
        __syncthreads();                                                     \
    }

    FFT_STAGE(2,   0.25f,         bufA, bufB)
    FFT_STAGE(4,   0.125f,        bufB, bufA)
    FFT_STAGE(8,   0.0625f,       bufA, bufB)
    FFT_STAGE(16,  0.03125f,      bufB, bufA)
    FFT_STAGE(32,  0.015625f,     bufA, bufB)
    FFT_STAGE(64,  0.0078125f,    bufB, bufA)
    FFT_STAGE(128, 0.00390625f,   bufA, bufB)
    #undef FFT_STAGE

    // ---------------- Stage Ns=256 -> coalesced store ----------------
    {
        float2 u = bufB[t];
        float2 v = bufB[t + 256];
        float rev = (float)t * 0.001953125f;   // t/512 revolutions
        float cw = vcos(rev), sw = vsin(rev);
        float vr = fmaf(cw, v.x, -sw * v.y);
        float vi = fmaf(cw, v.y,  sw * v.x);
        const float sc = 1.0f / 512.0f;
        float2* wsq = xout + ((size_t)qh << 9);
        wsq[t]       = make_float2((u.x + vr) * sc, (u.y + vi) * sc);
        wsq[t + 256] = make_float2((u.x - vr) * sc, (u.y - vi) * sc);
    }
}

// ---------- Kernel 2: x[q][h][s] -> out[s][q][h] ----------
__global__ __launch_bounds__(256)
void tssm_transpose(const float* __restrict__ x, float* __restrict__ out)
{
    __shared__ float tile[64][65];
    const int t  = threadIdx.x;
    const int hs = blockIdx.x;        // 0..3
    const int ss = blockIdx.y;        // 0..15
    const int q  = blockIdx.z;        // 0..3
    const int c  = t & 63;
    const int r0 = t >> 6;
    const int hbase = (q << 8) + (hs << 6);

    #pragma unroll
    for (int rr = 0; rr < 64; rr += 4) {
        int hh = hbase + rr + r0;
        tile[rr + r0][c] = x[(hh << 10) + (ss << 6) + c];
    }
    __syncthreads();
    #pragma unroll
    for (int rr = 0; rr < 64; rr += 4) {
        int s = (ss << 6) + rr + r0;
        out[(s << 10) + hbase + c] = tile[c][rr + r0];
    }
}

extern "C" void kernel_launch(void* const* d_in, const int* in_sizes, int n_in,
                              void* d_out, int out_size, void* d_ws, size_t ws_size,
                              hipStream_t stream) {
    (void)in_sizes; (void)n_in; (void)out_size; (void)ws_size;
    const float* diagonal      = (const float*)d_in[0];
    const float* lowrank       = (const float*)d_in[1];
    const float* timestep      = (const float*)d_in[2];
    const float* input_matrix  = (const float*)d_in[3];
    const float* output_matrix = (const float*)d_in[4];
    float* ws  = (float*)d_ws;
    float* out = (float*)d_out;

    const float* tabp  = ws;
    const float* sumsp = ws + SUMS_OFF;
    const float* tanp  = ws + TAN_OFF;
    float2*      xop   = (float2*)(ws + XBUF_OFF);
    const float* xinp  = ws + XBUF_OFF;

    hipLaunchKernelGGL(tssm_prep, dim3(258), dim3(256), 0, stream,
                       diagonal, lowrank, input_matrix, output_matrix, ws);
    hipLaunchKernelGGL(tssm_main, dim3(QQ * HH), dim3(256), 0, stream,
                       timestep, tabp, sumsp, tanp, xop);
    hipLaunchKernelGGL(tssm_transpose, dim3(4, 16, 4), dim3(256), 0, stream,
                       xinp, out);
}

// Round 11
// 26.328 us; speedup vs baseline: 1.4237x; 1.0842x over previous
//
#include <hip/hip_runtime.h>
#include <math.h>

// Problem constants: Q=4, N=64, H=256, C=1, L=1024
#define QQ 4
#define NN 64
#define HH 256

// Kernel 1: 512 blocks x 256 threads; block bp handles qh0=2bp (waves 0,1)
//   and qh1=2bp+1 (waves 2,3), 4 bins/thread -> half the waves of R5 =>
//   half the broadcast pole-table LDS traffic (the measured bottleneck).
//   Then two sequential 512-pt inverse Stockham FFTs (R5-proven numerics),
//   coalesced x writes to ws[qh][s].
// Kernel 2: proven 64x64 tile transpose ws[qh][s] -> out[s][qh].

__device__ __forceinline__ float vcos(float rev) { return __builtin_amdgcn_cosf(rev); }
__device__ __forceinline__ float vsin(float rev) { return __builtin_amdgcn_sinf(rev); }

__global__ __launch_bounds__(256)
void tssm_main(const float* __restrict__ diagonal,      // [Q][N]
               const float* __restrict__ lowrank,       // [Q][N]
               const float* __restrict__ timestep,      // [Q][H]
               const float* __restrict__ input_matrix,  // [Q][N]
               const float* __restrict__ output_matrix, // [Q][1][H][N]
               float* __restrict__ ws)                  // [Q*H][1024]
{
    __shared__ __align__(16) float2 sX[2][513];   // spectra (and FFT ping buffer)
    __shared__ __align__(16) float2 bufA[512];    // FFT pong buffer
    __shared__ __align__(16) float4 sP4[2][NN];   // (a, a^2, w0=B*C, w1=B*P)
    __shared__ __align__(8)  float2 sP2[2][NN];   // (w2=P*C, w3=P*P)

    const int bp = blockIdx.x;        // 0..511
    const int t  = threadIdx.x;       // 0..255

    // ---- pole tables: wave 0 -> qh0, wave 1 -> qh1; + X512 per qh ----
    if (t < 128) {
        const int jj = t >> 6;            // table 0 or 1
        const int n  = t & 63;
        const int qh = 2 * bp + jj;
        const int q  = qh >> 8;
        float a  = __expf(diagonal[q * NN + n]);
        float B  = input_matrix[q * NN + n];
        float P  = lowrank[q * NN + n];
        float Cm = output_matrix[qh * NN + n];
        float w0 = B * Cm;
        sP4[jj][n] = make_float4(a, a * a, w0, B * P);
        sP2[jj][n] = make_float2(P * Cm, P * P);
        float acc = w0;
        #pragma unroll
        for (int off = 32; off >= 1; off >>= 1) acc += __shfl_xor(acc, off, 64);
        if (n == 0) {
            float tvj = __expf(timestep[qh]);
            sX[jj][512] = make_float2(0.5f * tvj * acc, 0.0f);
        }
    }
    __syncthreads();

    // ---------------- Phase A: 4 bins per thread ----------------
    const int   j    = t >> 7;            // which qh this thread computes
    const int   tl   = t & 127;           // bins tl, tl+128, tl+256, tl+384
    const int   qh   = 2 * bp + j;
    const float tv   = __expf(timestep[qh]);
    const float invt = __builtin_amdgcn_rcpf(tv);

    float tn[4], ze[4], z2[4];
    #pragma unroll
    for (int k = 0; k < 4; ++k) {
        float f = (float)(tl + (k << 7)) * (1.0f / 1024.0f);
        tn[k] = sinpif(f) * __builtin_amdgcn_rcpf(cospif(f));
        ze[k] = 2.0f * tn[k] * invt;
        z2[k] = ze[k] * ze[k];
    }

    // Re k_w = sum w*a*g ; S_w = sum w*g ; Im k_w = -ze*S_w
    float rr[4][4] = {{0,0,0,0},{0,0,0,0},{0,0,0,0},{0,0,0,0}};
    float ss[4][4] = {{0,0,0,0},{0,0,0,0},{0,0,0,0},{0,0,0,0}};

    const float4* __restrict__ P4 = sP4[j];
    const float2* __restrict__ P2 = sP2[j];
    #pragma unroll 4
    for (int n = 0; n < NN; ++n) {
        float4 p4 = P4[n];
        float2 p2 = P2[n];
        #pragma unroll
        for (int k = 0; k < 4; ++k) {
            float g  = __builtin_amdgcn_rcpf(p4.y + z2[k]);
            float ag = p4.x * g;
            rr[k][0] = fmaf(p4.z, ag, rr[k][0]); ss[k][0] = fmaf(p4.z, g, ss[k][0]);
            rr[k][1] = fmaf(p4.w, ag, rr[k][1]); ss[k][1] = fmaf(p4.w, g, ss[k][1]);
            rr[k][2] = fmaf(p2.x, ag, rr[k][2]); ss[k][2] = fmaf(p2.x, g, ss[k][2]);
            rr[k][3] = fmaf(p2.y, ag, rr[k][3]); ss[k][3] = fmaf(p2.y, g, ss[k][3]);
        }
    }

    #pragma unroll
    for (int k = 0; k < 4; ++k) {
        float i0 = -ze[k] * ss[k][0], i1 = -ze[k] * ss[k][1];
        float i2 = -ze[k] * ss[k][2], i3 = -ze[k] * ss[k][3];
        float dr = 1.0f + rr[k][3], di = i3;
        float nr = rr[k][2] * rr[k][1] - i2 * i1;
        float ni = rr[k][2] * i1 + i2 * rr[k][1];
        float invm = __builtin_amdgcn_rcpf(fmaf(dr, dr, di * di));
        float qr = (nr * dr + ni * di) * invm;
        float qi = (ni * dr - nr * di) * invm;
        float Kr = rr[k][0] - qr, Ki = i0 - qi;
        sX[j][tl + (k << 7)] =
            make_float2(fmaf(-tn[k], Ki, Kr), fmaf(tn[k], Kr, Ki));
    }
    __syncthreads();

    // ---------------- Phase B: two sequential 512-pt inverse FFTs ----------------
    const float c1 = vcos((float)t * 0.0009765625f);   // cos(2*pi*t/1024)
    const float s1 = vsin((float)t * 0.0009765625f);

    for (int jj = 0; jj < 2; ++jj) {
        float2* X = sX[jj];

        // ---- Y build (k = t and k = t+256) ----
        float Y0r, Y0i, Y1r, Y1i;
        {   // k = t
            float2 A = X[t], Bv = X[512 - t];
            float Dr = A.x - Bv.x, Di = A.y + Bv.y;
            float twDr = fmaf(c1, Dr, -s1 * Di);
            float twDi = fmaf(c1, Di,  s1 * Dr);
            Y0r = 0.5f * (A.x + Bv.x) - 0.5f * twDi;
            Y0i = 0.5f * (A.y - Bv.y) + 0.5f * twDr;
        }
        {   // k = t+256
            float2 A = X[t + 256], Bv = X[256 - t];
            float Dr = A.x - Bv.x, Di = A.y + Bv.y;
            float twDr = fmaf(-s1, Dr, -c1 * Di);
            float twDi = fmaf(-s1, Di,  c1 * Dr);
            Y1r = 0.5f * (A.x + Bv.x) - 0.5f * twDi;
            Y1i = 0.5f * (A.y - Bv.y) + 0.5f * twDr;
        }

        // ---- Stage Ns=1 (registers) -> bufA ----
        ((float4*)bufA)[t] = make_float4(Y0r + Y1r, Y0i + Y1i, Y0r - Y1r, Y0i - Y1i);
        __syncthreads();

        // ---- Stages Ns = 2..128, ping-pong bufA <-> X ----
        #define FFT_STAGE(NS, REVNS, SRC, DST)                               \
        {                                                                    \
            float2 u = (SRC)[t];                                             \
            float2 v = (SRC)[t + 256];                                       \
            int   base = t & ((NS) - 1);                                     \
            float rev = (float)base * (REVNS);                               \
            float cw = vcos(rev), sw = vsin(rev);                            \
            float vr = fmaf(cw, v.x, -sw * v.y);                             \
            float vi = fmaf(cw, v.y,  sw * v.x);                             \
            int dj = ((t & ~((NS) - 1)) << 1) | base;                        \
            (DST)[dj]        = make_float2(u.x + vr, u.y + vi);              \
            (DST)[dj + (NS)] = make_float2(u.x - vr, u.y - vi);              \
            __syncthreads();                                                 \
        }

        FFT_STAGE(2,   0.25f,         bufA, X)
        FFT_STAGE(4,   0.125f,        X,    bufA)
        FFT_STAGE(8,   0.0625f,       bufA, X)
        FFT_STAGE(16,  0.03125f,      X,    bufA)
        FFT_STAGE(32,  0.015625f,     bufA, X)
        FFT_STAGE(64,  0.0078125f,    X,    bufA)
        FFT_STAGE(128, 0.00390625f,   bufA, X)
        #undef FFT_STAGE

        // ---- Stage Ns=256 -> coalesced ws store ----
        {
            float2 u = X[t];
            float2 v = X[t + 256];
            float rev = (float)t * 0.001953125f;   // t/512 revolutions
            float cw = vcos(rev), sw = vsin(rev);
            float vr = fmaf(cw, v.x, -sw * v.y);
            float vi = fmaf(cw, v.y,  sw * v.x);
            const float sc = 1.0f / 512.0f;
            float2* wsq = (float2*)ws + ((size_t)(2 * bp + jj) << 9);
            wsq[t]       = make_float2((u.x + vr) * sc, (u.y + vi) * sc);
            wsq[t + 256] = make_float2((u.x - vr) * sc, (u.y - vi) * sc);
        }
    }
}

// ---------- Kernel 2: x[q][h][s] -> out[s][q][h] ----------
__global__ __launch_bounds__(256)
void tssm_transpose(const float* __restrict__ x, float* __restrict__ out)
{
    __shared__ float tile[64][65];
    const int t  = threadIdx.x;
    const int hs = blockIdx.x;        // 0..3
    const int ss = blockIdx.y;        // 0..15
    const int q  = blockIdx.z;        // 0..3
    const int c  = t & 63;
    const int r0 = t >> 6;
    const int hbase = (q << 8) + (hs << 6);

    #pragma unroll
    for (int rr = 0; rr < 64; rr += 4) {
        int hh = hbase + rr + r0;
        tile[rr + r0][c] = x[(hh << 10) + (ss << 6) + c];
    }
    __syncthreads();
    #pragma unroll
    for (int rr = 0; rr < 64; rr += 4) {
        int s = (ss << 6) + rr + r0;
        out[(s << 10) + hbase + c] = tile[c][rr + r0];
    }
}

extern "C" void kernel_launch(void* const* d_in, const int* in_sizes, int n_in,
                              void* d_out, int out_size, void* d_ws, size_t ws_size,
                              hipStream_t stream) {
    (void)in_sizes; (void)n_in; (void)out_size; (void)ws_size;
    const float* diagonal      = (const float*)d_in[0];
    const float* lowrank       = (const float*)d_in[1];
    const float* timestep      = (const float*)d_in[2];
    const float* input_matrix  = (const float*)d_in[3];
    const float* output_matrix = (const float*)d_in[4];
    float* ws  = (float*)d_ws;
    float* out = (float*)d_out;

    hipLaunchKernelGGL(tssm_main, dim3(QQ * HH / 2), dim3(256), 0, stream,
                       diagonal, lowrank, timestep, input_matrix, output_matrix, ws);
    hipLaunchKernelGGL(tssm_transpose, dim3(4, 16, 4), dim3(256), 0, stream,
                       ws, out);
}

// Round 12
// 20.551 us; speedup vs baseline: 1.8240x; 1.2811x over previous
//
#include <hip/hip_runtime.h>
#include <math.h>

// Problem constants: Q=4, N=64, H=256, C=1, L=1024
#define QQ 4
#define NN 64
#define HH 256

// SINGLE kernel, 1024 blocks x 256 threads (R5-proven compute core).
// Block b -> qh via XCD-aware swizzle: qh = (b%8)*128 + b/8, so the 16
// consecutive-h blocks sharing each 64B output line run on ONE XCD and
// their 4B scattered stores merge in that XCD's writeback L2.
// Phase A: spectrum X[l] (LDS pole table, deferred-imag resolvent sums,
//          rank-1 correction), l = t, t+256.
// Phase B: irfft(1024) as 512-pt complex inverse Stockham FFT in LDS,
//          hardware v_sin/v_cos twiddles; final stage stores directly
//          to out[s][q][h] (scattered 4B, merged in L2).

__device__ __forceinline__ float vcos(float rev) { return __builtin_amdgcn_cosf(rev); }
__device__ __forceinline__ float vsin(float rev) { return __builtin_amdgcn_sinf(rev); }

__global__ __launch_bounds__(256)
void tssm_kernel(const float* __restrict__ diagonal,      // [Q][N]
                 const float* __restrict__ lowrank,       // [Q][N]
                 const float* __restrict__ timestep,      // [Q][H]
                 const float* __restrict__ input_matrix,  // [Q][N]
                 const float* __restrict__ output_matrix, // [Q][1][H][N]
                 float* __restrict__ out)                 // [L][Q][1][H]
{
    __shared__ __align__(16) float2 bufA[512];
    __shared__ __align__(16) float2 bufB[513];
    __shared__ __align__(16) float4 sP4[NN];   // (a, a^2, w0=B*C, w1=B*P)
    __shared__ __align__(8)  float2 sP2[NN];   // (w2=P*C, w3=P*P)

    const int b  = blockIdx.x;                  // 0..1023
    const int qh = ((b & 7) << 7) + (b >> 3);   // XCD-aware swizzle
    const int q  = qh >> 8;
    const int h  = qh & (HH - 1);
    const int t  = threadIdx.x;

    const float tv   = __expf(timestep[qh]);
    const float invt = __builtin_amdgcn_rcpf(tv);

    // ---- pole table setup (wave 0) + X[512] ----
    if (t < NN) {
        float a  = __expf(diagonal[q * NN + t]);
        float B  = input_matrix[q * NN + t];
        float P  = lowrank[q * NN + t];
        float Cm = output_matrix[qh * NN + t];
        float w0 = B * Cm;
        sP4[t] = make_float4(a, a * a, w0, B * P);
        sP2[t] = make_float2(P * Cm, P * P);
        float acc = w0;
        #pragma unroll
        for (int off = 32; off >= 1; off >>= 1) acc += __shfl_xor(acc, off, 64);
        if (t == 0) bufB[512] = make_float2(0.5f * tv * acc, 0.0f);
    }
    __syncthreads();

    // ---------------- Phase A ----------------
    const float f1  = (float)t         * (1.0f / 1024.0f);
    const float f2  = (float)(t + 256) * (1.0f / 1024.0f);
    const float tn0 = sinpif(f1) * __builtin_amdgcn_rcpf(cospif(f1));
    const float tn1 = sinpif(f2) * __builtin_amdgcn_rcpf(cospif(f2));
    const float ze0 = 2.0f * tn0 * invt, ze1 = 2.0f * tn1 * invt;
    const float z20 = ze0 * ze0,         z21 = ze1 * ze1;

    float r0_0=0,r0_1=0,r0_2=0,r0_3=0, s0_0=0,s0_1=0,s0_2=0,s0_3=0;
    float r1_0=0,r1_1=0,r1_2=0,r1_3=0, s1_0=0,s1_1=0,s1_2=0,s1_3=0;

    #pragma unroll 8
    for (int n = 0; n < NN; ++n) {
        float4 p4 = sP4[n];
        float2 p2 = sP2[n];
        {
            float g  = __builtin_amdgcn_rcpf(p4.y + z20);
            float ag = p4.x * g;
            r0_0 = fmaf(p4.z, ag, r0_0); s0_0 = fmaf(p4.z, g, s0_0);
            r0_1 = fmaf(p4.w, ag, r0_1); s0_1 = fmaf(p4.w, g, s0_1);
            r0_2 = fmaf(p2.x, ag, r0_2); s0_2 = fmaf(p2.x, g, s0_2);
            r0_3 = fmaf(p2.y, ag, r0_3); s0_3 = fmaf(p2.y, g, s0_3);
        }
        {
            float g  = __builtin_amdgcn_rcpf(p4.y + z21);
            float ag = p4.x * g;
            r1_0 = fmaf(p4.z, ag, r1_0); s1_0 = fmaf(p4.z, g, s1_0);
            r1_1 = fmaf(p4.w, ag, r1_1); s1_1 = fmaf(p4.w, g, s1_1);
            r1_2 = fmaf(p2.x, ag, r1_2); s1_2 = fmaf(p2.x, g, s1_2);
            r1_3 = fmaf(p2.y, ag, r1_3); s1_3 = fmaf(p2.y, g, s1_3);
        }
    }

    {   // bin l = t
        float i0 = -ze0 * s0_0, i1 = -ze0 * s0_1, i2 = -ze0 * s0_2, i3 = -ze0 * s0_3;
        float dr = 1.0f + r0_3, di = i3;
        float nr = r0_2 * r0_1 - i2 * i1;
        float ni = r0_2 * i1 + i2 * r0_1;
        float invm = __builtin_amdgcn_rcpf(fmaf(dr, dr, di * di));
        float qr = (nr * dr + ni * di) * invm;
        float qi = (ni * dr - nr * di) * invm;
        float Kr = r0_0 - qr, Ki = i0 - qi;
        bufB[t] = make_float2(fmaf(-tn0, Ki, Kr), fmaf(tn0, Kr, Ki));
    }
    {   // bin l = t + 256
        float i0 = -ze1 * s1_0, i1 = -ze1 * s1_1, i2 = -ze1 * s1_2, i3 = -ze1 * s1_3;
        float dr = 1.0f + r1_3, di = i3;
        float nr = r1_2 * r1_1 - i2 * i1;
        float ni = r1_2 * i1 + i2 * r1_1;
        float invm = __builtin_amdgcn_rcpf(fmaf(dr, dr, di * di));
        float qr = (nr * dr + ni * di) * invm;
        float qi = (ni * dr - nr * di) * invm;
        float Kr = r1_0 - qr, Ki = i0 - qi;
        bufB[t + 256] = make_float2(fmaf(-tn1, Ki, Kr), fmaf(tn1, Kr, Ki));
    }
    __syncthreads();

    // ---------------- Y build ----------------
    const float c1 = vcos((float)t * 0.0009765625f);   // cos(2*pi*t/1024)
    const float s1 = vsin((float)t * 0.0009765625f);

    float Y0r, Y0i, Y1r, Y1i;
    {   // k = t
        float2 A = bufB[t], Bv = bufB[512 - t];
        float Dr = A.x - Bv.x, Di = A.y + Bv.y;
        float twDr = fmaf(c1, Dr, -s1 * Di);
        float twDi = fmaf(c1, Di,  s1 * Dr);
        Y0r = 0.5f * (A.x + Bv.x) - 0.5f * twDi;
        Y0i = 0.5f * (A.y - Bv.y) + 0.5f * twDr;
    }
    {   // k = t+256
        float2 A = bufB[t + 256], Bv = bufB[256 - t];
        float Dr = A.x - Bv.x, Di = A.y + Bv.y;
        float twDr = fmaf(-s1, Dr, -c1 * Di);
        float twDi = fmaf(-s1, Di,  c1 * Dr);
        Y1r = 0.5f * (A.x + Bv.x) - 0.5f * twDi;
        Y1i = 0.5f * (A.y - Bv.y) + 0.5f * twDr;
    }

    // ---------------- Stage Ns=1 (registers) ----------------
    ((float4*)bufA)[t] = make_float4(Y0r + Y1r, Y0i + Y1i, Y0r - Y1r, Y0i - Y1i);
    __syncthreads();

    // ---------------- Stages Ns = 2..128 ----------------
    #define FFT_STAGE(NS, REVNS, SRC, DST)                                   \
    {                                                                        \
        float2 u = (SRC)[t];                                                 \
        float2 v = (SRC)[t + 256];                                           \
        int   base = t & ((NS) - 1);                                         \
        float rev = (float)base * (REVNS);                                   \
        float cw = vcos(rev), sw = vsin(rev);                                \
        float vr = fmaf(cw, v.x, -sw * v.y);                                 \
        float vi = fmaf(cw, v.y,  sw * v.x);                                 \
        int dj = ((t & ~((NS) - 1)) << 1) | base;                            \
        (DST)[dj]        = make_float2(u.x + vr, u.y + vi);                  \
        (DST)[dj + (NS)] = make_float2(u.x - vr, u.y - vi);                  \
        __syncthreads();                                                     \
    }

    FFT_STAGE(2,   0.25f,         bufA, bufB)
    FFT_STAGE(4,   0.125f,        bufB, bufA)
    FFT_STAGE(8,   0.0625f,       bufA, bufB)
    FFT_STAGE(16,  0.03125f,      bufB, bufA)
    FFT_STAGE(32,  0.015625f,     bufA, bufB)
    FFT_STAGE(64,  0.0078125f,    bufB, bufA)
    FFT_STAGE(128, 0.00390625f,   bufA, bufB)
    #undef FFT_STAGE

    // -------- Stage Ns=256 -> direct scattered store to out[s][q][h] --------
    {
        float2 u = bufB[t];
        float2 v = bufB[t + 256];
        float rev = (float)t * 0.001953125f;   // t/512 revolutions
        float cw = vcos(rev), sw = vsin(rev);
        float vr = fmaf(cw, v.x, -sw * v.y);
        float vi = fmaf(cw, v.y,  sw * v.x);
        const float sc = 1.0f / 512.0f;
        // y[t]     -> x[2t], x[2t+1]
        // y[t+256] -> x[2t+512], x[2t+513]
        const int s0 = 2 * t;
        out[( s0        << 10) + qh] = (u.x + vr) * sc;
        out[((s0 + 1)   << 10) + qh] = (u.y + vi) * sc;
        out[((s0 + 512) << 10) + qh] = (u.x - vr) * sc;
        out[((s0 + 513) << 10) + qh] = (u.y - vi) * sc;
    }
}

extern "C" void kernel_launch(void* const* d_in, const int* in_sizes, int n_in,
                              void* d_out, int out_size, void* d_ws, size_t ws_size,
                              hipStream_t stream) {
    (void)in_sizes; (void)n_in; (void)out_size; (void)d_ws; (void)ws_size;
    const float* diagonal      = (const float*)d_in[0];
    const float* lowrank       = (const float*)d_in[1];
    const float* timestep      = (const float*)d_in[2];
    const float* input_matrix  = (const float*)d_in[3];
    const float* output_matrix = (const float*)d_in[4];
    float* out = (float*)d_out;

    hipLaunchKernelGGL(tssm_kernel, dim3(QQ * HH), dim3(256), 0, stream,
                       diagonal, lowrank, timestep, input_matrix, output_matrix, out);
}